// Round 6
// baseline (888.497 us; speedup 1.0000x reference)
//
#include <hip/hip_runtime.h>
#include <math.h>

#define D_MODEL 1024
#define NH 16
#define DK 64
#define BB 2
#define SS 2048
#define BH (BB * NH)      // 32
#define M_TOT (BB * SS)   // 4096
#define NQT (SS / 64)     // 32 q-tiles per (b,h)

typedef __bf16 bf16x8 __attribute__((ext_vector_type(8)));
typedef float f32x4 __attribute__((ext_vector_type(4)));

static __device__ __forceinline__ unsigned short f2bf(float x) {
  unsigned int u = __float_as_uint(x);
  u = (u + 0x7fffu + ((u >> 16) & 1u)) >> 16;  // RNE
  return (unsigned short)u;
}

// ---------------------------------------------------------------------------
// fp32 -> bf16 elementwise convert (n8 = elements/8)
// ---------------------------------------------------------------------------
__global__ __launch_bounds__(256) void cvt_bf16_82592221102086(
    const float* __restrict__ src, unsigned short* __restrict__ dst, int n8) {
  int i = blockIdx.x * blockDim.x + threadIdx.x;
  if (i >= n8) return;
  const float4* s = reinterpret_cast<const float4*>(src) + 2 * (size_t)i;
  float4 a = s[0], b = s[1];
  union { unsigned short us[8]; uint4 u4; } pk;
  pk.us[0] = f2bf(a.x); pk.us[1] = f2bf(a.y);
  pk.us[2] = f2bf(a.z); pk.us[3] = f2bf(a.w);
  pk.us[4] = f2bf(b.x); pk.us[5] = f2bf(b.y);
  pk.us[6] = f2bf(b.z); pk.us[7] = f2bf(b.w);
  *(reinterpret_cast<uint4*>(dst) + i) = pk.u4;
}

// ---------------------------------------------------------------------------
// MFMA GEMM: y[m,n] = sum_k X[m,k]*W[n,k] + bias[n]   (X, W bf16, k-contig)
// Tile 128(m) x 64(n), BK=64, 256 threads = 4 waves; wave owns 32 rows.
// MODE 0: write bf16 head-split [b,h,s,dk]   MODE 1: write fp32 [m,n]
// ---------------------------------------------------------------------------
template <int MODE>
__global__ __launch_bounds__(256) void proj_mfma_82592221102086(
    const unsigned short* __restrict__ X, const unsigned short* __restrict__ W,
    const float* __restrict__ bias, void* __restrict__ Yv) {
  __shared__ __align__(16) unsigned short As[128][72];
  __shared__ __align__(16) unsigned short Bs[64][72];
  const int tid = threadIdx.x;
  const int wave = tid >> 6, lane = tid & 63;
  const int lrow = lane & 15, lkc = lane >> 4;  // frag row, k-chunk
  const int m0 = blockIdx.y * 128, n0 = blockIdx.x * 64;

  f32x4 acc[2][4] = {};

  for (int kt = 0; kt < D_MODEL; kt += 64) {
    __syncthreads();
#pragma unroll
    for (int i = 0; i < 4; ++i) {  // A: 128 rows x 8 chunks
      int c = tid + 256 * i, r = c >> 3, c8 = (c & 7) * 8;
      *reinterpret_cast<uint4*>(&As[r][c8]) = *reinterpret_cast<const uint4*>(
          &X[(size_t)(m0 + r) * D_MODEL + kt + c8]);
    }
#pragma unroll
    for (int i = 0; i < 2; ++i) {  // B: 64 rows x 8 chunks
      int c = tid + 256 * i, r = c >> 3, c8 = (c & 7) * 8;
      *reinterpret_cast<uint4*>(&Bs[r][c8]) = *reinterpret_cast<const uint4*>(
          &W[(size_t)(n0 + r) * D_MODEL + kt + c8]);
    }
    __syncthreads();
#pragma unroll
    for (int kk = 0; kk < 64; kk += 32) {
      bf16x8 a0 = *reinterpret_cast<const bf16x8*>(
          &As[wave * 32 + lrow][kk + lkc * 8]);
      bf16x8 a1 = *reinterpret_cast<const bf16x8*>(
          &As[wave * 32 + 16 + lrow][kk + lkc * 8]);
#pragma unroll
      for (int nj = 0; nj < 4; ++nj) {
        bf16x8 b = *reinterpret_cast<const bf16x8*>(
            &Bs[nj * 16 + lrow][kk + lkc * 8]);
        acc[0][nj] = __builtin_amdgcn_mfma_f32_16x16x32_bf16(a0, b, acc[0][nj], 0, 0, 0);
        acc[1][nj] = __builtin_amdgcn_mfma_f32_16x16x32_bf16(a1, b, acc[1][nj], 0, 0, 0);
      }
    }
  }

  const int h = n0 >> 6;  // MODE 0: this block covers exactly one head
#pragma unroll
  for (int mi = 0; mi < 2; ++mi) {
#pragma unroll
    for (int nj = 0; nj < 4; ++nj) {
      const int d = nj * 16 + lrow;
      const float bv = bias[n0 + d];
#pragma unroll
      for (int j = 0; j < 4; ++j) {
        const int m = m0 + wave * 32 + mi * 16 + lkc * 4 + j;
        const float val = acc[mi][nj][j] + bv;
        if (MODE == 0) {
          const int b = m >> 11, s = m & 2047;
          reinterpret_cast<unsigned short*>(Yv)
              [((size_t)(b * NH + h) * SS + s) * DK + d] = f2bf(val);
        } else {
          reinterpret_cast<float*>(Yv)[(size_t)m * D_MODEL + n0 + d] = val;
        }
      }
    }
  }
}

// ---------------------------------------------------------------------------
// Two-pass MFMA causal attention, one (b,h) x one 64-row q-tile per block.
// 4 waves, each owns 16 q rows; Q frags in registers.
// Pass A: QK^T + exp -> row sums only.  Pass B: recompute QK^T, write
// NORMALIZED p (fp32, nontemporal) to attn, PV with normalized bf16 frags.
// Epilogue: zero-fill this block's upper-triangle tiles (write-balanced:
// every block writes exactly 32 tiles = 512 KB of attn).
// Block swizzle: XCD x gets bh in [4x,4x+4) -> K/V set 2 MB/XCD (L2-resident).
// ---------------------------------------------------------------------------
__global__ __launch_bounds__(256) void attn_mfma_82592221102086(
    const unsigned short* __restrict__ qb, const unsigned short* __restrict__ kb,
    const unsigned short* __restrict__ vb, float* __restrict__ attn,
    unsigned short* __restrict__ ctx) {
  __shared__ __align__(16) unsigned short Ks[64][72];  // [t][d]
  __shared__ __align__(16) unsigned short Vt[64][72];  // [d][t-swizzled]
  __shared__ __align__(16) unsigned short Ps[64][72];  // [qrow][t] bf16
  const int bi = blockIdx.x;          // 0..1023
  const int xcd = bi & 7, slot = bi >> 3;
  const int bh = xcd * 4 + (slot >> 5);
  const int qt = slot & 31;
  const int qs = qt * 64;
  const int tid = threadIdx.x;
  const int wave = tid >> 6, lane = tid & 63;
  const int lrow = lane & 15, lkc = lane >> 4;

  // Q fragments (rows qs + wave*16 + lrow)
  const unsigned short* qrow =
      qb + ((size_t)bh * SS + qs + wave * 16 + lrow) * DK;
  bf16x8 qf[2];
  qf[0] = *reinterpret_cast<const bf16x8*>(qrow + lkc * 8);
  qf[1] = *reinterpret_cast<const bf16x8*>(qrow + 32 + lkc * 8);

  float lsum[4] = {};

  // ---------------- Pass A: row sums ----------------
  for (int kt = 0; kt <= qt; ++kt) {
    const int ks = kt * 64;
    __syncthreads();
#pragma unroll
    for (int i = 0; i < 2; ++i) {
      int c = tid + 256 * i, r = c >> 3, c8 = (c & 7) * 8;
      *reinterpret_cast<uint4*>(&Ks[r][c8]) = *reinterpret_cast<const uint4*>(
          &kb[((size_t)bh * SS + ks + r) * DK + c8]);
    }
    __syncthreads();

    f32x4 sacc[4] = {};
#pragma unroll
    for (int kk = 0; kk < 64; kk += 32) {
      const int idx = kk >> 5;
#pragma unroll
      for (int tj = 0; tj < 4; ++tj) {
        bf16x8 kf = *reinterpret_cast<const bf16x8*>(
            &Ks[tj * 16 + lrow][kk + lkc * 8]);
        sacc[tj] = __builtin_amdgcn_mfma_f32_16x16x32_bf16(qf[idx], kf, sacc[tj], 0, 0, 0);
      }
    }
    const bool diag = (kt == qt);
#pragma unroll
    for (int tj = 0; tj < 4; ++tj) {
#pragma unroll
      for (int j = 0; j < 4; ++j) {
        const int grow = qs + wave * 16 + lkc * 4 + j;
        const int gcol = ks + tj * 16 + lrow;
        if (!diag || gcol <= grow)
          lsum[j] += __expf(fminf(sacc[tj][j] * 0.125f, 80.f));
      }
    }
  }

  // reduce row sums over the 16-lane col groups; inv per lane-row
  float inv[4];
#pragma unroll
  for (int j = 0; j < 4; ++j) {
    float l = lsum[j];
#pragma unroll
    for (int m = 1; m < 16; m <<= 1) l += __shfl_xor(l, m, 64);
    inv[j] = 1.0f / l;
  }

  // ---------------- Pass B: normalized p write + PV ----------------
  f32x4 oacc[4] = {};

  for (int kt = 0; kt <= qt; ++kt) {
    const int ks = kt * 64;
    __syncthreads();
#pragma unroll
    for (int i = 0; i < 2; ++i) {
      int c = tid + 256 * i, r = c >> 3, c8 = (c & 7) * 8;
      *reinterpret_cast<uint4*>(&Ks[r][c8]) = *reinterpret_cast<const uint4*>(
          &kb[((size_t)bh * SS + ks + r) * DK + c8]);
    }
    // stage V transposed+swizzled: element V[t][d] -> Vt[d][t ^ 8*((d>>3)&7)]
#pragma unroll
    for (int i = 0; i < 2; ++i) {
      int c = tid + 256 * i, t = c >> 3, d0 = (c & 7) * 8;
      uint4 raw = *reinterpret_cast<const uint4*>(
          &vb[((size_t)bh * SS + ks + t) * DK + d0]);
      const unsigned short* pv = reinterpret_cast<const unsigned short*>(&raw);
      const int tsw = t ^ d0;  // 8*((d0/8)&7) == d0 for d0 in {0..56}
#pragma unroll
      for (int jj = 0; jj < 8; ++jj) Vt[d0 + jj][tsw] = pv[jj];
    }
    __syncthreads();

    f32x4 sacc[4] = {};
#pragma unroll
    for (int kk = 0; kk < 64; kk += 32) {
      const int idx = kk >> 5;
#pragma unroll
      for (int tj = 0; tj < 4; ++tj) {
        bf16x8 kf = *reinterpret_cast<const bf16x8*>(
            &Ks[tj * 16 + lrow][kk + lkc * 8]);
        sacc[tj] = __builtin_amdgcn_mfma_f32_16x16x32_bf16(qf[idx], kf, sacc[tj], 0, 0, 0);
      }
    }

    const bool diag = (kt == qt);
#pragma unroll
    for (int tj = 0; tj < 4; ++tj) {
#pragma unroll
      for (int j = 0; j < 4; ++j) {
        const int prow = lkc * 4 + j;
        const int grow = qs + wave * 16 + prow;
        const int gcol = ks + tj * 16 + lrow;
        float pv = 0.f;
        if (!diag || gcol <= grow)
          pv = __expf(fminf(sacc[tj][j] * 0.125f, 80.f)) * inv[j];
        __builtin_nontemporal_store(
            pv, &attn[((size_t)bh * SS + grow) * SS + gcol]);
        Ps[wave * 16 + prow][tj * 16 + lrow] = f2bf(pv);
      }
    }
    // No barrier needed: each wave reads only its own 16 Ps rows (in-order
    // same-wave LDS RAW -> compiler waitcnt), Vt was covered by the sync above.
#pragma unroll
    for (int kk2 = 0; kk2 < 64; kk2 += 32) {
      bf16x8 pf = *reinterpret_cast<const bf16x8*>(
          &Ps[wave * 16 + lrow][kk2 + lkc * 8]);
#pragma unroll
      for (int dj = 0; dj < 4; ++dj) {
        const int d = dj * 16 + lrow;
        const int tch = ((kk2 >> 3) + lkc) ^ (d >> 3);  // swizzled t-chunk
        bf16x8 vf = *reinterpret_cast<const bf16x8*>(&Vt[d][tch << 3]);
        oacc[dj] = __builtin_amdgcn_mfma_f32_16x16x32_bf16(pf, vf, oacc[dj], 0, 0, 0);
      }
    }
  }

  // ---------------- context write (already normalized) ----------------
  const int b = bh >> 4, h = bh & 15;
#pragma unroll
  for (int dj = 0; dj < 4; ++dj) {
    const int d = dj * 16 + lrow;
#pragma unroll
    for (int j = 0; j < 4; ++j) {
      const int row = qs + wave * 16 + lkc * 4 + j;
      ctx[((size_t)(b * SS + row)) * D_MODEL + h * DK + d] =
          f2bf(oacc[dj][j]);
    }
  }

  // ---------------- zero-fill upper-triangle tiles ----------------
  const f32x4 z4 = {0.f, 0.f, 0.f, 0.f};
  for (int kt = qt + 1; kt < NQT; ++kt) {
    const int ks = kt * 64;
#pragma unroll
    for (int u = 0; u < 4; ++u) {
      const int idx = tid + 256 * u;       // 0..1023
      const int r = idx >> 4, c4 = idx & 15;
      __builtin_nontemporal_store(
          z4, reinterpret_cast<f32x4*>(
                  &attn[((size_t)bh * SS + qs + r) * SS + ks + c4 * 4]));
    }
  }
}

// ---------------------------------------------------------------------------
extern "C" void kernel_launch(void* const* d_in, const int* in_sizes, int n_in,
                              void* d_out, int out_size, void* d_ws,
                              size_t ws_size, hipStream_t stream) {
  const float* Q = (const float*)d_in[0];
  const float* K = (const float*)d_in[1];
  const float* V = (const float*)d_in[2];
  const float* Wq = (const float*)d_in[4];
  const float* bq = (const float*)d_in[5];
  const float* Wk = (const float*)d_in[6];
  const float* bk = (const float*)d_in[7];
  const float* Wv = (const float*)d_in[8];
  const float* bv = (const float*)d_in[9];
  const float* Wo = (const float*)d_in[10];
  const float* bo = (const float*)d_in[11];

  float* out = (float*)d_out;                   // [B,S,D_MODEL] fp32
  float* attn = out + (size_t)M_TOT * D_MODEL;  // [B,H,S,S] fp32

  const size_t nX = (size_t)M_TOT * D_MODEL;  // 4,194,304
  const size_t nW = (size_t)D_MODEL * D_MODEL;
  unsigned short* ws = (unsigned short*)d_ws;
  unsigned short* Qc = ws;
  unsigned short* Kc = Qc + nX;
  unsigned short* Vc = Kc + nX;
  unsigned short* Wqc = Vc + nX;
  unsigned short* Wkc = Wqc + nW;
  unsigned short* Wvc = Wkc + nW;
  unsigned short* Woc = Wvc + nW;
  unsigned short* qbv = Woc + nW;
  unsigned short* kbv = qbv + nX;
  unsigned short* vbv = kbv + nX;
  unsigned short* ctx = vbv + nX;

  cvt_bf16_82592221102086<<<(nX / 8 + 255) / 256, 256, 0, stream>>>(Q, Qc, nX / 8);
  cvt_bf16_82592221102086<<<(nX / 8 + 255) / 256, 256, 0, stream>>>(K, Kc, nX / 8);
  cvt_bf16_82592221102086<<<(nX / 8 + 255) / 256, 256, 0, stream>>>(V, Vc, nX / 8);
  cvt_bf16_82592221102086<<<(nW / 8 + 255) / 256, 256, 0, stream>>>(Wq, Wqc, nW / 8);
  cvt_bf16_82592221102086<<<(nW / 8 + 255) / 256, 256, 0, stream>>>(Wk, Wkc, nW / 8);
  cvt_bf16_82592221102086<<<(nW / 8 + 255) / 256, 256, 0, stream>>>(Wv, Wvc, nW / 8);
  cvt_bf16_82592221102086<<<(nW / 8 + 255) / 256, 256, 0, stream>>>(Wo, Woc, nW / 8);

  const dim3 gGemm(D_MODEL / 64, M_TOT / 128);
  proj_mfma_82592221102086<0><<<gGemm, 256, 0, stream>>>(Qc, Wqc, bq, qbv);
  proj_mfma_82592221102086<0><<<gGemm, 256, 0, stream>>>(Kc, Wkc, bk, kbv);
  proj_mfma_82592221102086<0><<<gGemm, 256, 0, stream>>>(Vc, Wvc, bv, vbv);

  attn_mfma_82592221102086<<<dim3(NQT * BH), 256, 0, stream>>>(
      qbv, kbv, vbv, attn, ctx);

  proj_mfma_82592221102086<1><<<gGemm, 256, 0, stream>>>(ctx, Woc, bo, out);
}

// Round 7
// 789.527 us; speedup vs baseline: 1.1254x; 1.1254x over previous
//
#include <hip/hip_runtime.h>
#include <math.h>

#define D_MODEL 1024
#define NH 16
#define DK 64
#define BB 2
#define SS 2048
#define BH (BB * NH)      // 32
#define M_TOT (BB * SS)   // 4096
#define QBLK 128
#define NSTRIP (SS / QBLK)  // 16

typedef __bf16 bf16x8 __attribute__((ext_vector_type(8)));
typedef float f32x4 __attribute__((ext_vector_type(4)));

static __device__ __forceinline__ unsigned short f2bf(float x) {
  unsigned int u = __float_as_uint(x);
  u = (u + 0x7fffu + ((u >> 16) & 1u)) >> 16;  // RNE
  return (unsigned short)u;
}

// ---------------------------------------------------------------------------
// Fused fp32 -> bf16 convert for all 7 tensors (one dispatch).
// Blocks 0..6143: Q,K,V (2048 blocks each). 6144..8191: Wq,Wk,Wv,Wo (512 each).
// Each block converts 2048 elems (256 thr x 8).
// ---------------------------------------------------------------------------
__global__ __launch_bounds__(256) void cvt_all_82592221102086(
    const float* __restrict__ Q, const float* __restrict__ K,
    const float* __restrict__ V, const float* __restrict__ Wq,
    const float* __restrict__ Wk, const float* __restrict__ Wv,
    const float* __restrict__ Wo, unsigned short* __restrict__ Qc,
    unsigned short* __restrict__ Kc, unsigned short* __restrict__ Vc,
    unsigned short* __restrict__ Wqc, unsigned short* __restrict__ Wkc,
    unsigned short* __restrict__ Wvc, unsigned short* __restrict__ Woc) {
  const int id = blockIdx.x;
  const float* s;
  unsigned short* d;
  int c0;
  if (id < 2048) { s = Q; d = Qc; c0 = id * 256; }
  else if (id < 4096) { s = K; d = Kc; c0 = (id - 2048) * 256; }
  else if (id < 6144) { s = V; d = Vc; c0 = (id - 4096) * 256; }
  else {
    const int w = (id - 6144) >> 9, off = (id - 6144) & 511;
    s = (w == 0) ? Wq : (w == 1) ? Wk : (w == 2) ? Wv : Wo;
    d = (w == 0) ? Wqc : (w == 1) ? Wkc : (w == 2) ? Wvc : Woc;
    c0 = off * 256;
  }
  const size_t i = (size_t)c0 + threadIdx.x;  // uint4 chunk (8 elems)
  const float4* sp = reinterpret_cast<const float4*>(s) + 2 * i;
  float4 a = sp[0], b = sp[1];
  union { unsigned short us[8]; uint4 u4; } pk;
  pk.us[0] = f2bf(a.x); pk.us[1] = f2bf(a.y);
  pk.us[2] = f2bf(a.z); pk.us[3] = f2bf(a.w);
  pk.us[4] = f2bf(b.x); pk.us[5] = f2bf(b.y);
  pk.us[6] = f2bf(b.z); pk.us[7] = f2bf(b.w);
  *(reinterpret_cast<uint4*>(d) + i) = pk.u4;
}

// ---------------------------------------------------------------------------
// GEMM body: y[m,n] = sum_k X[m,k]*W[n,k] + bias[n]   (X, W bf16, k-contig)
// Tile 128(m) x 64(n), BK=64, 256 threads = 4 waves.
// MODE 0: write bf16 head-split [b,h,s,dk]   MODE 1: write fp32 [m,n]
// ---------------------------------------------------------------------------
template <int MODE>
static __device__ __forceinline__ void proj_body(
    const unsigned short* __restrict__ X, const unsigned short* __restrict__ W,
    const float* __restrict__ bias, void* __restrict__ Yv, int m0, int n0) {
  __shared__ __align__(16) unsigned short As[128][72];
  __shared__ __align__(16) unsigned short Bs[64][72];
  const int tid = threadIdx.x;
  const int wave = tid >> 6, lane = tid & 63;
  const int lrow = lane & 15, lkc = lane >> 4;

  f32x4 acc[2][4] = {};

  for (int kt = 0; kt < D_MODEL; kt += 64) {
    __syncthreads();
#pragma unroll
    for (int i = 0; i < 4; ++i) {
      int c = tid + 256 * i, r = c >> 3, c8 = (c & 7) * 8;
      *reinterpret_cast<uint4*>(&As[r][c8]) = *reinterpret_cast<const uint4*>(
          &X[(size_t)(m0 + r) * D_MODEL + kt + c8]);
    }
#pragma unroll
    for (int i = 0; i < 2; ++i) {
      int c = tid + 256 * i, r = c >> 3, c8 = (c & 7) * 8;
      *reinterpret_cast<uint4*>(&Bs[r][c8]) = *reinterpret_cast<const uint4*>(
          &W[(size_t)(n0 + r) * D_MODEL + kt + c8]);
    }
    __syncthreads();
#pragma unroll
    for (int kk = 0; kk < 64; kk += 32) {
      bf16x8 a0 = *reinterpret_cast<const bf16x8*>(
          &As[wave * 32 + lrow][kk + lkc * 8]);
      bf16x8 a1 = *reinterpret_cast<const bf16x8*>(
          &As[wave * 32 + 16 + lrow][kk + lkc * 8]);
#pragma unroll
      for (int nj = 0; nj < 4; ++nj) {
        bf16x8 b = *reinterpret_cast<const bf16x8*>(
            &Bs[nj * 16 + lrow][kk + lkc * 8]);
        acc[0][nj] = __builtin_amdgcn_mfma_f32_16x16x32_bf16(a0, b, acc[0][nj], 0, 0, 0);
        acc[1][nj] = __builtin_amdgcn_mfma_f32_16x16x32_bf16(a1, b, acc[1][nj], 0, 0, 0);
      }
    }
  }

  const int h = n0 >> 6;
#pragma unroll
  for (int mi = 0; mi < 2; ++mi) {
#pragma unroll
    for (int nj = 0; nj < 4; ++nj) {
      const int d = nj * 16 + lrow;
      const float bv = bias[n0 + d];
#pragma unroll
      for (int j = 0; j < 4; ++j) {
        const int m = m0 + wave * 32 + mi * 16 + lkc * 4 + j;
        const float val = acc[mi][nj][j] + bv;
        if (MODE == 0) {
          const int b = m >> 11, s = m & 2047;
          reinterpret_cast<unsigned short*>(Yv)
              [((size_t)(b * NH + h) * SS + s) * DK + d] = f2bf(val);
        } else {
          reinterpret_cast<float*>(Yv)[(size_t)m * D_MODEL + n0 + d] = val;
        }
      }
    }
  }
}

// Fused Q/K/V projections: blockIdx.z picks the GEMM.
__global__ __launch_bounds__(256) void proj_qkv_82592221102086(
    const unsigned short* __restrict__ Qc, const unsigned short* __restrict__ Kc,
    const unsigned short* __restrict__ Vc, const unsigned short* __restrict__ Wqc,
    const unsigned short* __restrict__ Wkc, const unsigned short* __restrict__ Wvc,
    const float* __restrict__ bq, const float* __restrict__ bk,
    const float* __restrict__ bv, unsigned short* __restrict__ qbv,
    unsigned short* __restrict__ kbv, unsigned short* __restrict__ vbv) {
  const unsigned short *X, *W;
  const float* bias;
  unsigned short* Y;
  if (blockIdx.z == 0) { X = Qc; W = Wqc; bias = bq; Y = qbv; }
  else if (blockIdx.z == 1) { X = Kc; W = Wkc; bias = bk; Y = kbv; }
  else { X = Vc; W = Wvc; bias = bv; Y = vbv; }
  proj_body<0>(X, W, bias, Y, blockIdx.y * 128, blockIdx.x * 64);
}

__global__ __launch_bounds__(256) void proj_out_82592221102086(
    const unsigned short* __restrict__ X, const unsigned short* __restrict__ W,
    const float* __restrict__ bias, float* __restrict__ Y) {
  proj_body<1>(X, W, bias, Y, blockIdx.y * 128, blockIdx.x * 64);
}

// ---------------------------------------------------------------------------
// Two-pass MFMA causal attention. One (b,h) x one 128-row q strip per block.
// 512 threads = 8 waves, each wave owns 16 q rows. KV tiles of 64.
// Pass A: QK^T + exp -> row sums. Pass B: recompute, write NORMALIZED p via
// LDS-staged f32x4 coalesced nontemporal stores, PV with bf16 frags.
// Per-block attn write is constant 1 MB (ntile p-tiles + rest zero-filled).
// qt complement pairing balances compute across co-resident block pairs.
// ---------------------------------------------------------------------------
__global__ __launch_bounds__(512, 4) void attn_mfma_82592221102086(
    const unsigned short* __restrict__ qb, const unsigned short* __restrict__ kb,
    const unsigned short* __restrict__ vb, float* __restrict__ attn,
    unsigned short* __restrict__ ctx) {
  __shared__ __align__(16) unsigned short Ks[64][72];   // [t][d]
  __shared__ __align__(16) unsigned short Vt[64][72];   // [d][t-swizzled]
  __shared__ __align__(16) unsigned short Ps[QBLK][76];  // [qrow][t] bf16
  __shared__ __align__(16) float Pf[QBLK][76];           // [qrow][t] fp32

  const int bi = blockIdx.x;                // 0..511
  const int xcd = bi & 7, slot = bi >> 3;   // slot 0..63
  const int bhl = (slot >> 4) & 3;
  const int bh = xcd * 4 + bhl;
  const int u = slot & 15;
  const int qt = (bhl & 2) ? (15 - u) : u;  // complementary qt pairing
  const int qs = qt * QBLK;
  const int ntile = 2 * qt + 2;             // kv tiles with data
  const int tid = threadIdx.x;
  const int wave = tid >> 6, lane = tid & 63;
  const int lrow = lane & 15, lkc = lane >> 4;

  // Q fragments: rows qs + wave*16 + lrow
  const unsigned short* qrow =
      qb + ((size_t)bh * SS + qs + wave * 16 + lrow) * DK;
  const bf16x8 qf0 = *reinterpret_cast<const bf16x8*>(qrow + lkc * 8);
  const bf16x8 qf1 = *reinterpret_cast<const bf16x8*>(qrow + 32 + lkc * 8);

  float lsum[4] = {};

  // ---------------- Pass A: row sums ----------------
  for (int kt = 0; kt < ntile; ++kt) {
    const int ks = kt * 64;
    __syncthreads();
    {  // stage K tile: 512 uint4 chunks, one per thread
      const int r = tid >> 3, c8 = (tid & 7) * 8;
      *reinterpret_cast<uint4*>(&Ks[r][c8]) = *reinterpret_cast<const uint4*>(
          &kb[((size_t)bh * SS + ks + r) * DK + c8]);
    }
    __syncthreads();

    f32x4 sacc[4] = {};
#pragma unroll
    for (int kk = 0; kk < 64; kk += 32) {
      const bf16x8 qf = (kk == 0) ? qf0 : qf1;
#pragma unroll
      for (int tj = 0; tj < 4; ++tj) {
        bf16x8 kf = *reinterpret_cast<const bf16x8*>(
            &Ks[tj * 16 + lrow][kk + lkc * 8]);
        sacc[tj] = __builtin_amdgcn_mfma_f32_16x16x32_bf16(qf, kf, sacc[tj], 0, 0, 0);
      }
    }
    const bool diag = (kt >= ntile - 2);
#pragma unroll
    for (int tj = 0; tj < 4; ++tj) {
#pragma unroll
      for (int j = 0; j < 4; ++j) {
        const int grow = qs + wave * 16 + lkc * 4 + j;
        const int gcol = ks + tj * 16 + lrow;
        if (!diag || gcol <= grow)
          lsum[j] += __expf(fminf(sacc[tj][j] * 0.125f, 80.f));
      }
    }
  }

  // reduce row sums over the 16 lanes of each col group
  float inv[4];
#pragma unroll
  for (int j = 0; j < 4; ++j) {
    float l = lsum[j];
#pragma unroll
    for (int m = 1; m < 16; m <<= 1) l += __shfl_xor(l, m, 64);
    inv[j] = 1.0f / l;
  }

  // ---------------- Pass B: normalized p write + PV ----------------
  f32x4 oacc[4] = {};

  for (int kt = 0; kt < ntile; ++kt) {
    const int ks = kt * 64;
    __syncthreads();
    {  // stage K
      const int r = tid >> 3, c8 = (tid & 7) * 8;
      *reinterpret_cast<uint4*>(&Ks[r][c8]) = *reinterpret_cast<const uint4*>(
          &kb[((size_t)bh * SS + ks + r) * DK + c8]);
    }
    {  // stage V transposed+swizzled: V[t][d] -> Vt[d][t ^ 8*((d>>3)&7)]
      const int t = tid >> 3, d0 = (tid & 7) * 8;
      uint4 raw = *reinterpret_cast<const uint4*>(
          &vb[((size_t)bh * SS + ks + t) * DK + d0]);
      const unsigned short* pv = reinterpret_cast<const unsigned short*>(&raw);
      const int tsw = t ^ d0;  // d0 = 8*(d0/8)
#pragma unroll
      for (int jj = 0; jj < 8; ++jj) Vt[d0 + jj][tsw] = pv[jj];
    }
    __syncthreads();

    f32x4 sacc[4] = {};
#pragma unroll
    for (int kk = 0; kk < 64; kk += 32) {
      const bf16x8 qf = (kk == 0) ? qf0 : qf1;
#pragma unroll
      for (int tj = 0; tj < 4; ++tj) {
        bf16x8 kf = *reinterpret_cast<const bf16x8*>(
            &Ks[tj * 16 + lrow][kk + lkc * 8]);
        sacc[tj] = __builtin_amdgcn_mfma_f32_16x16x32_bf16(qf, kf, sacc[tj], 0, 0, 0);
      }
    }

    const bool diag = (kt >= ntile - 2);
#pragma unroll
    for (int tj = 0; tj < 4; ++tj) {
#pragma unroll
      for (int j = 0; j < 4; ++j) {
        const int prow = wave * 16 + lkc * 4 + j;
        const int grow = qs + prow;
        const int gcol = ks + tj * 16 + lrow;
        float pv = 0.f;
        if (!diag || gcol <= grow)
          pv = __expf(fminf(sacc[tj][j] * 0.125f, 80.f)) * inv[j];
        Pf[prow][tj * 16 + lrow] = pv;
        Ps[prow][tj * 16 + lrow] = f2bf(pv);
      }
    }
    __syncthreads();  // Pf/Ps complete for the whole strip

    // coalesced nontemporal f32x4 stores of the 128x64 p tile
#pragma unroll
    for (int it = 0; it < 4; ++it) {
      const int r = it * 32 + (tid >> 4), c0 = (tid & 15) * 4;
      const f32x4 v = *reinterpret_cast<const f32x4*>(&Pf[r][c0]);
      __builtin_nontemporal_store(
          v, reinterpret_cast<f32x4*>(
                 &attn[((size_t)bh * SS + qs + r) * SS + ks + c0]));
    }

    // PV: own-wave Ps rows (same-wave RAW), Vt protected by loop-top barrier
#pragma unroll
    for (int kk2 = 0; kk2 < 64; kk2 += 32) {
      bf16x8 pf = *reinterpret_cast<const bf16x8*>(
          &Ps[wave * 16 + lrow][kk2 + lkc * 8]);
#pragma unroll
      for (int dj = 0; dj < 4; ++dj) {
        const int d = dj * 16 + lrow;
        const int tch = ((kk2 >> 3) + lkc) ^ (d >> 3);
        bf16x8 vf = *reinterpret_cast<const bf16x8*>(&Vt[d][tch << 3]);
        oacc[dj] = __builtin_amdgcn_mfma_f32_16x16x32_bf16(pf, vf, oacc[dj], 0, 0, 0);
      }
    }
  }

  // ---------------- context write (already normalized) ----------------
  const int b = bh >> 4, h = bh & 15;
#pragma unroll
  for (int dj = 0; dj < 4; ++dj) {
    const int d = dj * 16 + lrow;
#pragma unroll
    for (int j = 0; j < 4; ++j) {
      const int row = qs + wave * 16 + lkc * 4 + j;
      ctx[((size_t)(b * SS + row)) * D_MODEL + h * DK + d] = f2bf(oacc[dj][j]);
    }
  }

  // ---------------- zero-fill remaining tiles ----------------
  const f32x4 z4 = {0.f, 0.f, 0.f, 0.f};
  for (int kt = ntile; kt < 32; ++kt) {
    const int ks = kt * 64;
#pragma unroll
    for (int it = 0; it < 4; ++it) {
      const int r = it * 32 + (tid >> 4), c0 = (tid & 15) * 4;
      __builtin_nontemporal_store(
          z4, reinterpret_cast<f32x4*>(
                  &attn[((size_t)bh * SS + qs + r) * SS + ks + c0]));
    }
  }
}

// ---------------------------------------------------------------------------
extern "C" void kernel_launch(void* const* d_in, const int* in_sizes, int n_in,
                              void* d_out, int out_size, void* d_ws,
                              size_t ws_size, hipStream_t stream) {
  const float* Q = (const float*)d_in[0];
  const float* K = (const float*)d_in[1];
  const float* V = (const float*)d_in[2];
  const float* Wq = (const float*)d_in[4];
  const float* bq = (const float*)d_in[5];
  const float* Wk = (const float*)d_in[6];
  const float* bk = (const float*)d_in[7];
  const float* Wv = (const float*)d_in[8];
  const float* bv = (const float*)d_in[9];
  const float* Wo = (const float*)d_in[10];
  const float* bo = (const float*)d_in[11];

  float* out = (float*)d_out;                   // [B,S,D_MODEL] fp32
  float* attn = out + (size_t)M_TOT * D_MODEL;  // [B,H,S,S] fp32

  const size_t nX = (size_t)M_TOT * D_MODEL;  // 4,194,304
  const size_t nW = (size_t)D_MODEL * D_MODEL;
  unsigned short* ws = (unsigned short*)d_ws;
  unsigned short* Qc = ws;
  unsigned short* Kc = Qc + nX;
  unsigned short* Vc = Kc + nX;
  unsigned short* Wqc = Vc + nX;
  unsigned short* Wkc = Wqc + nW;
  unsigned short* Wvc = Wkc + nW;
  unsigned short* Woc = Wvc + nW;
  unsigned short* qbv = Woc + nW;
  unsigned short* kbv = qbv + nX;
  unsigned short* vbv = kbv + nX;
  unsigned short* ctx = vbv + nX;

  cvt_all_82592221102086<<<8192, 256, 0, stream>>>(
      Q, K, V, Wq, Wk, Wv, Wo, Qc, Kc, Vc, Wqc, Wkc, Wvc, Woc);

  proj_qkv_82592221102086<<<dim3(D_MODEL / 64, M_TOT / 128, 3), 256, 0,
                            stream>>>(Qc, Kc, Vc, Wqc, Wkc, Wvc, bq, bk, bv,
                                      qbv, kbv, vbv);

  attn_mfma_82592221102086<<<dim3(BH * NSTRIP), 512, 0, stream>>>(
      qbv, kbv, vbv, attn, ctx);

  proj_out_82592221102086<<<dim3(D_MODEL / 64, M_TOT / 128), 256, 0, stream>>>(
      ctx, Woc, bo, out);
}